// Round 9
// baseline (129.646 us; speedup 1.0000x reference)
//
#include <hip/hip_runtime.h>

#define DIN 512
#define DOUT 512
#define BM 64

typedef int v4i __attribute__((ext_vector_type(4)));
typedef float v4f __attribute__((ext_vector_type(4)));

#define WAITVM(n) asm volatile("s_waitcnt vmcnt(" #n ")" ::: "memory")
#define WAITLGKM0() asm volatile("s_waitcnt lgkmcnt(0)" ::: "memory")

// exact-divide quantize (weights/bias path, matches ref bit-for-bit)
__device__ __forceinline__ int q8f(float v, float s) {
    int i = (int)rintf(v / s);
    i = i < -128 ? -128 : (i > 127 ? 127 : i);
    return i & 255;
}
// multiply-by-reciprocal quantize (activation path; flip prob ~2^-22)
__device__ __forceinline__ int q8m(float v, float inv) {
    int i = (int)rintf(v * inv);
    i = i < -128 ? -128 : (i > 127 ? 127 : i);
    return i & 255;
}

// ---------------- Kernel 1: global absmax of x ----------------
__global__ void absmax_kernel(const float4* __restrict__ x4, unsigned* __restrict__ amax, int n4) {
    float m = 0.f;
    int stride = gridDim.x * blockDim.x;
    for (int i = blockIdx.x * blockDim.x + threadIdx.x; i < n4; i += stride) {
        float4 v = x4[i];
        m = fmaxf(m, fmaxf(fmaxf(fabsf(v.x), fabsf(v.y)), fmaxf(fabsf(v.z), fabsf(v.w))));
    }
#pragma unroll
    for (int off = 32; off; off >>= 1) m = fmaxf(m, __shfl_xor(m, off));
    __shared__ float sm[4];
    int lane = threadIdx.x & 63, w = threadIdx.x >> 6;
    if (lane == 0) sm[w] = m;
    __syncthreads();
    if (threadIdx.x == 0) {
        m = fmaxf(fmaxf(sm[0], sm[1]), fmaxf(sm[2], sm[3]));
        atomicMax(amax, __float_as_uint(m));  // positive floats: uint compare == float compare
    }
}

// ---------------- Kernel 2: per-row weight quant ----------------
__global__ void quantw_kernel(const float* __restrict__ w,
                              char* __restrict__ wq, float* __restrict__ wsc) {
    int gid = blockIdx.x * blockDim.x + threadIdx.x;
    int row = gid >> 6, lane = gid & 63;
    const float4* r4 = (const float4*)(w + (long)row * DIN);
    float4 a = r4[lane * 2];
    float4 b = r4[lane * 2 + 1];
    float m = fmaxf(fmaxf(fmaxf(fabsf(a.x), fabsf(a.y)), fabsf(a.z)),
                    fmaxf(fmaxf(fabsf(a.w), fabsf(b.x)),
                          fmaxf(fmaxf(fabsf(b.y), fabsf(b.z)), fabsf(b.w))));
#pragma unroll
    for (int off = 32; off; off >>= 1) m = fmaxf(m, __shfl_xor(m, off));
    float s = m / 127.0f;
    int lo = q8f(a.x, s) | (q8f(a.y, s) << 8) | (q8f(a.z, s) << 16) | (q8f(a.w, s) << 24);
    int hi = q8f(b.x, s) | (q8f(b.y, s) << 8) | (q8f(b.z, s) << 16) | (q8f(b.w, s) << 24);
    ((int2*)(wq + (long)row * DIN))[lane] = make_int2(lo, hi);
    if (lane == 0) wsc[row] = s;
}

// ---------------- Kernel 2b: combined scales + quantized bias ----------------
__global__ void quantb_kernel(const float* __restrict__ bias, const float* __restrict__ wsc,
                              const unsigned* __restrict__ amax,
                              float* __restrict__ bs, float* __restrict__ bq) {
    int oc = threadIdx.x;
    float as = __uint_as_float(*amax) / 127.0f;
    float s = as * wsc[oc];
    bs[oc] = s;
    bq[oc] = rintf(bias[oc] / s) * s;
}

// ---------------- Kernel 2c: quantize x once into chunk-linear int8 ----------------
// x8 layout per 64-row tile T: byte = T*32768 + ks*4096
//   + ((row>>4)*64 + kq*16 + (row&15))*16 + (byte-in-16)   [kq = 16B k-quarter]
// == the validated R7/R8 xl LDS layout, replicated per k-step. A wave's MFMA
// B-frag (16-row chunk mi, step ks) is then CONTIGUOUS 1KB at base+lane*16.
__global__ __launch_bounds__(512) void quantx_kernel(
    const float* __restrict__ x, const unsigned* __restrict__ amax,
    char* __restrict__ x8) {
    const int t = threadIdx.x;
    const long T = blockIdx.x;
    const float as = __uint_as_float(*amax) / 127.0f;
    const float inv_as = 1.0f / as;
    const int xrow = t >> 3, xc = t & 7;
    const float* src = x + (T * 64 + xrow) * DIN + xc * 8;
    char* dst = x8 + T * 32768 +
                ((xrow >> 4) * 64 + (xc >> 1) * 16 + (xrow & 15)) * 16 + (xc & 1) * 8;
    float4 v[16];
#pragma unroll
    for (int ks = 0; ks < 8; ks++) {
        v[2 * ks]     = *(const float4*)(src + ks * 64);
        v[2 * ks + 1] = *(const float4*)(src + ks * 64 + 4);
    }
#pragma unroll
    for (int ks = 0; ks < 8; ks++) {
        float4 a = v[2 * ks], b = v[2 * ks + 1];
        int lo = q8m(a.x, inv_as) | (q8m(a.y, inv_as) << 8) |
                 (q8m(a.z, inv_as) << 16) | (q8m(a.w, inv_as) << 24);
        int hi = q8m(b.x, inv_as) | (q8m(b.y, inv_as) << 8) |
                 (q8m(b.z, inv_as) << 16) | (q8m(b.w, inv_as) << 24);
        *(int2*)(dst + ks * 4096) = make_int2(lo, hi);
    }
}

// ---------------- Kernel 3: pure int8 GEMM (x8 pre-quantized) ----------------
// BM=64 x BN=512, 512 thr / 8 waves (2m x 4oc), wave tile 32m x 128oc.
// x B-frags: direct global->VGPR (contiguous 1KB, L2/L3-resident 33.5MB), 1-step
// prefetch, compiler-managed waits. w: LDS dbuf 2x32KB via global_load_lds,
// counted vmcnt(6) BEFORE each barrier (fixes R7's cross-wave DMA race:
// every wave's own w(ks) chunks are complete at barrier arrival). 16 MFMA/step,
// near-zero VALU. Epilogue: R8's LDS-transposed full-line nt stores.
__global__ __launch_bounds__(512, 4) void gemm_kernel(
    const char* __restrict__ x8, const char* __restrict__ wq,
    const float* __restrict__ bs, const float* __restrict__ bq,
    float* __restrict__ out) {
    __shared__ char wl[2][32768];   // dbuf w; reused as 64KB f32 out-stage
    const int t = threadIdx.x, lane = t & 63, wid = t >> 6;
    const int wm = wid >> 2, wn = wid & 3;
    const long rbase = (long)blockIdx.x * BM;
    const char* wgsrc = wq + ((wid * 64) + (lane & 15)) * DIN + (lane >> 4) * 16;
    const char* xtile = x8 + (long)blockIdx.x * 32768 + (wm * 2) * 1024 + lane * 16;

    v4i xa[2][2];
    v4i acc[2][8] = {};

#define DMAW(n, b) { _Pragma("unroll") for (int jj = 0; jj < 4; jj++) \
    __builtin_amdgcn_global_load_lds( \
        (const __attribute__((address_space(1))) unsigned*)(wgsrc + jj * 16 * DIN + (n) * 64), \
        (__attribute__((address_space(3))) unsigned*)(wl[b] + (wid * 4 + jj) * 1024), 16, 0, 0); }
#define LDXF(n) { xa[(n) & 1][0] = *(const v4i*)(xtile + (n) * 4096); \
                  xa[(n) & 1][1] = *(const v4i*)(xtile + (n) * 4096 + 1024); }
#define COMPUTE(p) { _Pragma("unroll") for (int ni = 0; ni < 8; ni++) { \
    v4i wb = *(const v4i*)&wl[p][(wn * 8 + ni) * 1024 + lane * 16]; \
    acc[0][ni] = __builtin_amdgcn_mfma_i32_16x16x64_i8(wb, xa[p][0], acc[0][ni], 0, 0, 0); \
    acc[1][ni] = __builtin_amdgcn_mfma_i32_16x16x64_i8(wb, xa[p][1], acc[1][ni], 0, 0, 0); } }
// Per step KS: in-flight after LDXF = {w(KS):4(draining), x(KS):2, w(KS+1):4, x(KS+1):2}
// WAITVM(6) drains w(KS)+x(KS); leaves {w(KS+1):4, x(KS+1):2}. Barrier then makes
// every wave's w(KS) chunks globally visible. Post-compute barrier frees buf KS&1
// for DMAW(KS+2). vmcnt never drains to 0 until the last step.
#define STEP(KS) { \
    if ((KS) + 1 < 8) { LDXF((KS) + 1); WAITVM(6); } else { WAITVM(0); } \
    __builtin_amdgcn_s_barrier(); \
    COMPUTE((KS) & 1); \
    __builtin_amdgcn_s_barrier(); \
    if ((KS) + 2 < 8) DMAW((KS) + 2, (KS) & 1); }

    LDXF(0);
    DMAW(0, 0);
    DMAW(1, 1);
    STEP(0) STEP(1) STEP(2) STEP(3) STEP(4) STEP(5) STEP(6) STEP(7)

    // ---- epilogue: LDS-transposed full-line nt stores (STEP(7) ended with barrier)
    char* ostage = (char*)wl;       // 32 x 2048B rows = 64 KB
    const int mloc = lane & 15, ocr = (lane >> 4) * 4;
    const char* outb = (char*)out + rbase * 2048 + t * 16;
#pragma unroll
    for (int h = 0; h < 2; h++) {
        if (wm == h) {
#pragma unroll
            for (int ni = 0; ni < 8; ni++) {
                int oc0 = wn * 128 + ni * 16 + ocr;
                float4 s4 = *(const float4*)(bs + oc0);
                float4 q4 = *(const float4*)(bq + oc0);
#pragma unroll
                for (int mi = 0; mi < 2; mi++) {
                    int row = mi * 16 + mloc;
                    v4f v;
                    v[0] = (float)acc[mi][ni][0] * s4.x + q4.x;
                    v[1] = (float)acc[mi][ni][1] * s4.y + q4.y;
                    v[2] = (float)acc[mi][ni][2] * s4.z + q4.z;
                    v[3] = (float)acc[mi][ni][3] * s4.w + q4.w;
                    int byte = (row * 2048 + oc0 * 4) ^ ((row & 15) << 4);
                    *(v4f*)(ostage + byte) = v;
                }
            }
        }
        WAITLGKM0();
        __builtin_amdgcn_s_barrier();
#pragma unroll
        for (int i = 0; i < 8; i++) {
            int flat = t * 16 + i * 8192;
            int row = flat >> 11;
            v4f v = *(const v4f*)(ostage + (flat ^ ((row & 15) << 4)));
            __builtin_nontemporal_store(v, (v4f*)(outb + h * 65536 + i * 8192));
        }
        if (h == 0) {
            WAITLGKM0();
            __builtin_amdgcn_s_barrier();   // reads done before h=1 overwrites
        }
    }
#undef DMAW
#undef LDXF
#undef COMPUTE
#undef STEP
}

// ---------------- Fallback GEMM (R8 path, used if ws too small for x8) ----------------
__global__ __launch_bounds__(512, 4) void gemm_fb_kernel(
    const float* __restrict__ x, const char* __restrict__ wq,
    const float* __restrict__ bs, const float* __restrict__ bq,
    const unsigned* __restrict__ amax, float* __restrict__ out) {
    __shared__ char xl[2][BM * 64];
    __shared__ char wl[2][DOUT * 64];
    const int t = threadIdx.x, lane = t & 63, wid = t >> 6;
    const int wm = wid >> 2, wn = wid & 3;
    const long rbase = (long)blockIdx.x * BM;
    const float as = __uint_as_float(*amax) / 127.0f;
    const float inv_as = 1.0f / as;
    const int xrow = t >> 3, xc = t & 7;
    const float4* xg = (const float4*)(x + (rbase + xrow) * DIN) + xc * 2;
    const int xw_off = ((xrow >> 4) * 64 + (xc >> 1) * 16 + (xrow & 15)) * 16 + (xc & 1) * 8;
    const char* wgsrc = wq + ((wid * 64) + (lane & 15)) * DIN + (lane >> 4) * 16;
    float4 xv[2][2];
    v4i acc[2][8] = {};
#define LOADX(n, s) { const float4* p_ = xg + (n) * 16; xv[s][0] = p_[0]; xv[s][1] = p_[1]; }
#define DMAW(n, b) { _Pragma("unroll") for (int jj = 0; jj < 4; jj++) \
    __builtin_amdgcn_global_load_lds( \
        (const __attribute__((address_space(1))) unsigned*)(wgsrc + jj * 16 * DIN + (n) * 64), \
        (__attribute__((address_space(3))) unsigned*)(wl[b] + (wid * 4 + jj) * 1024), 16, 0, 0); }
#define QUANTX(s, b) { \
    int lo_ = q8m(xv[s][0].x, inv_as) | (q8m(xv[s][0].y, inv_as) << 8) | \
              (q8m(xv[s][0].z, inv_as) << 16) | (q8m(xv[s][0].w, inv_as) << 24); \
    int hi_ = q8m(xv[s][1].x, inv_as) | (q8m(xv[s][1].y, inv_as) << 8) | \
              (q8m(xv[s][1].z, inv_as) << 16) | (q8m(xv[s][1].w, inv_as) << 24); \
    *(int2*)&xl[b][xw_off] = make_int2(lo_, hi_); }
#define COMPUTE(p) { \
    v4i xa0 = *(const v4i*)&xl[p][(wm * 2 + 0) * 1024 + lane * 16]; \
    v4i xa1 = *(const v4i*)&xl[p][(wm * 2 + 1) * 1024 + lane * 16]; \
    _Pragma("unroll") for (int ni = 0; ni < 8; ni++) { \
        v4i wb = *(const v4i*)&wl[p][(wn * 8 + ni) * 1024 + lane * 16]; \
        acc[0][ni] = __builtin_amdgcn_mfma_i32_16x16x64_i8(wb, xa0, acc[0][ni], 0, 0, 0); \
        acc[1][ni] = __builtin_amdgcn_mfma_i32_16x16x64_i8(wb, xa1, acc[1][ni], 0, 0, 0); } }
    LOADX(0, 0); DMAW(0, 0); LOADX(1, 1);
    WAITVM(6); QUANTX(0, 0); WAITLGKM0(); __builtin_amdgcn_s_barrier();
#define STEP_MID(KS, PB) \
    DMAW(KS + 1, PB ^ 1); LOADX(KS + 2, (KS) & 1); \
    WAITVM(8); COMPUTE(PB); WAITVM(6); QUANTX((KS + 1) & 1, PB ^ 1); \
    WAITLGKM0(); __builtin_amdgcn_s_barrier();
    STEP_MID(0, 0) STEP_MID(1, 1) STEP_MID(2, 0) STEP_MID(3, 1) STEP_MID(4, 0) STEP_MID(5, 1)
    DMAW(7, 1); WAITVM(6); COMPUTE(0); WAITVM(4); QUANTX(1, 1);
    WAITLGKM0(); __builtin_amdgcn_s_barrier();
    WAITVM(0); COMPUTE(1);
    __builtin_amdgcn_s_barrier();
    char* ostage = (char*)wl;
    const int mloc = lane & 15, ocr = (lane >> 4) * 4;
    const char* outb = (char*)out + rbase * 2048 + t * 16;
#pragma unroll
    for (int h = 0; h < 2; h++) {
        if (wm == h) {
#pragma unroll
            for (int ni = 0; ni < 8; ni++) {
                int oc0 = wn * 128 + ni * 16 + ocr;
                float4 s4 = *(const float4*)(bs + oc0);
                float4 q4 = *(const float4*)(bq + oc0);
#pragma unroll
                for (int mi = 0; mi < 2; mi++) {
                    int row = mi * 16 + mloc;
                    v4f v;
                    v[0] = (float)acc[mi][ni][0] * s4.x + q4.x;
                    v[1] = (float)acc[mi][ni][1] * s4.y + q4.y;
                    v[2] = (float)acc[mi][ni][2] * s4.z + q4.z;
                    v[3] = (float)acc[mi][ni][3] * s4.w + q4.w;
                    int byte = (row * 2048 + oc0 * 4) ^ ((row & 15) << 4);
                    *(v4f*)(ostage + byte) = v;
                }
            }
        }
        WAITLGKM0();
        __builtin_amdgcn_s_barrier();
#pragma unroll
        for (int i = 0; i < 8; i++) {
            int flat = t * 16 + i * 8192;
            int row = flat >> 11;
            v4f v = *(const v4f*)(ostage + (flat ^ ((row & 15) << 4)));
            __builtin_nontemporal_store(v, (v4f*)(outb + h * 65536 + i * 8192));
        }
        if (h == 0) { WAITLGKM0(); __builtin_amdgcn_s_barrier(); }
    }
#undef LOADX
#undef DMAW
#undef QUANTX
#undef COMPUTE
#undef STEP_MID
}

extern "C" void kernel_launch(void* const* d_in, const int* in_sizes, int n_in,
                              void* d_out, int out_size, void* d_ws, size_t ws_size,
                              hipStream_t stream) {
    const float* x    = (const float*)d_in[0];
    const float* w    = (const float*)d_in[1];
    const float* bias = (const float*)d_in[2];
    float* out = (float*)d_out;
    const int M = in_sizes[0] / DIN;   // 65536

    char* ws = (char*)d_ws;
    unsigned* amax = (unsigned*)ws;
    char* wq   = ws + 64;
    float* wsc = (float*)(ws + 64 + (long)DOUT * DIN);
    float* bs  = wsc + DOUT;
    float* bq  = bs + DOUT;
    char* x8   = (char*)(bq + DOUT);
    const size_t need = 64 + (size_t)DOUT * DIN + 3 * DOUT * 4 + (size_t)M * DIN;

    hipMemsetAsync(d_ws, 0, 64, stream);
    quantw_kernel<<<(DOUT * 64) / 256, 256, 0, stream>>>(w, wq, wsc);
    absmax_kernel<<<2048, 256, 0, stream>>>((const float4*)x, amax, in_sizes[0] / 4);
    quantb_kernel<<<1, DOUT, 0, stream>>>(bias, wsc, amax, bs, bq);
    if (ws_size >= need) {
        quantx_kernel<<<M / 64, 512, 0, stream>>>(x, amax, x8);
        gemm_kernel<<<M / BM, 512, 0, stream>>>(x8, wq, bs, bq, out);
    } else {
        gemm_fb_kernel<<<M / BM, 512, 0, stream>>>(x, wq, bs, bq, amax, out);
    }
}